// Round 6
// baseline (1752.439 us; speedup 1.0000x reference)
//
#include <hip/hip_runtime.h>
#include <math.h>

#define T_   2048
#define DIN  512
#define H_   384
#define H4_  1536
#define BT_  16384

typedef _Float16 half_t;
typedef _Float16 f16x8 __attribute__((ext_vector_type(8)));
typedef float f32x4 __attribute__((ext_vector_type(4)));

#define LO_SCALE 2048.0f
#define LO_INV   4.8828125e-4f

// lgkm-only barrier: prefetched global->VGPR loads stay in flight across it.
__device__ __forceinline__ void lds_barrier() {
    asm volatile("s_waitcnt lgkmcnt(0)\n\ts_barrier" ::: "memory");
}

// full-drain barrier for the DMA-staged kernel: waits the global_load_lds set
// issued this iteration (vmcnt) and any LDS ops (lgkm), then syncs.
__device__ __forceinline__ void vm_barrier() {
    asm volatile("s_waitcnt vmcnt(0) lgkmcnt(0)\n\ts_barrier" ::: "memory");
}

// async global->LDS DMA, 16 B per lane (1 KB per wave-instruction).
// LDS dest is wave-uniform base + lane*16 (linear); global src is per-lane.
__device__ __forceinline__ void gload_lds(const half_t* g, half_t* l) {
    __builtin_amdgcn_global_load_lds(
        (const __attribute__((address_space(1))) unsigned int*)(const void*)g,
        (__attribute__((address_space(3))) unsigned int*)(void*)l, 16, 0, 0);
}

__device__ __forceinline__ void split2(float v, half_t* hi, half_t* lo) {
    half_t h = (half_t)v;
    *hi = h;
    *lo = (half_t)((v - (float)h) * LO_SCALE);
}

// ---------------------------------------------------------------------------
// fp32 -> (hi, lo*2048) fp16 element-wise split
// ---------------------------------------------------------------------------
__global__ void k_split(const float* __restrict__ in, half_t* __restrict__ hi,
                        half_t* __restrict__ lo, long n) {
    long i = (long)blockIdx.x * 256 + threadIdx.x;
    if (i >= n) return;
    split2(in[i], hi + i, lo + i);
}

// enc_w [H][DIN][7] -> [H][tap*512+i] hi/lo
__global__ void k_split_encw(const float* __restrict__ in, half_t* __restrict__ hi,
                             half_t* __restrict__ lo) {
    int idx = blockIdx.x * 256 + threadIdx.x;
    if (idx >= H_ * 3584) return;
    int n = idx / 3584;
    int r = idx % 3584;
    int tap = r >> 9, i = r & 511;
    split2(in[n * 3584 + i * 7 + tap], hi + idx, lo + idx);
}

// ---------------------------------------------------------------------------
// Row-wise LayerNorm over H=384 (fp32 in/out, in-place safe), one wave per row
// ---------------------------------------------------------------------------
__global__ void k_ln(const float* __restrict__ in, float* __restrict__ out,
                     const float* __restrict__ g, const float* __restrict__ b) {
    int row = blockIdx.x;
    int lane = threadIdx.x;
    const float* ir = in + (long)row * H_;
    float v[6];
    float s = 0.f;
#pragma unroll
    for (int j = 0; j < 6; ++j) { v[j] = ir[lane + (j << 6)]; s += v[j]; }
#pragma unroll
    for (int o = 32; o > 0; o >>= 1) s += __shfl_down(s, o, 64);
    s = __shfl(s, 0, 64);
    float mean = s * (1.f / 384.f);
    float q = 0.f;
#pragma unroll
    for (int j = 0; j < 6; ++j) { float d = v[j] - mean; q += d * d; }
#pragma unroll
    for (int o = 32; o > 0; o >>= 1) q += __shfl_down(q, o, 64);
    q = __shfl(q, 0, 64);
    float rstd = rsqrtf(q * (1.f / 384.f) + 1e-5f);
    float* orow = out + (long)row * H_;
#pragma unroll
    for (int j = 0; j < 6; ++j) {
        int c = lane + (j << 6);
        orow[c] = (v[j] - mean) * rstd * g[c] + b[c];
    }
}

// ---------------------------------------------------------------------------
// Fused depthwise conv (k=7, pad=3) + LayerNorm; emits fp16 hi/lo for GEMM1.
// float2-vectorized h loads (G13).
// ---------------------------------------------------------------------------
__global__ __launch_bounds__(256) void k_dwconv_ln(
    const float* __restrict__ h, half_t* __restrict__ oh,
    half_t* __restrict__ ol,
    const float* __restrict__ w, const float* __restrict__ wb,
    const float* __restrict__ g, const float* __restrict__ gb) {
    int row = (blockIdx.x << 2) + (threadIdx.x >> 6);
    int b = row >> 11;
    int t = row & 2047;
    int lane = threadIdx.x & 63;
    const float* hb = h + ((long)b * T_) * H_;
    float vx[3], vy[3];
    float s = 0.f;
#pragma unroll
    for (int j = 0; j < 3; ++j) {
        int c = (lane << 1) + (j << 7);
        float ax = wb[c], ay = wb[c + 1];
        const float* wcx = w + c * 7;
        const float* wcy = wcx + 7;
#pragma unroll
        for (int k = 0; k < 7; ++k) {
            int tt = t + k - 3;
            if ((unsigned)tt < (unsigned)T_) {
                float2 hv = *(const float2*)&hb[(long)tt * H_ + c];
                ax = fmaf(hv.x, wcx[k], ax);
                ay = fmaf(hv.y, wcy[k], ay);
            }
        }
        vx[j] = ax; vy[j] = ay;
        s += ax + ay;
    }
#pragma unroll
    for (int o = 32; o > 0; o >>= 1) s += __shfl_down(s, o, 64);
    s = __shfl(s, 0, 64);
    float mean = s * (1.f / 384.f);
    float q = 0.f;
#pragma unroll
    for (int j = 0; j < 3; ++j) {
        float dx = vx[j] - mean, dy = vy[j] - mean;
        q += dx * dx + dy * dy;
    }
#pragma unroll
    for (int o = 32; o > 0; o >>= 1) q += __shfl_down(q, o, 64);
    q = __shfl(q, 0, 64);
    float rstd = rsqrtf(q * (1.f / 384.f) + 1e-5f);
    long ro = (long)row * H_;
#pragma unroll
    for (int j = 0; j < 3; ++j) {
        int c = (lane << 1) + (j << 7);
        float valx = (vx[j] - mean) * rstd * g[c] + gb[c];
        float valy = (vy[j] - mean) * rstd * g[c + 1] + gb[c + 1];
        split2(valx, oh + ro + c, ol + ro + c);
        split2(valy, oh + ro + c + 1, ol + ro + c + 1);
    }
}

// ---------------------------------------------------------------------------
// Prefetch register sets as NAMED float4s via macros (never struct/reference —
// round-1: address-taken sets scratch-spill; rule #20).
// ---------------------------------------------------------------------------
#define DECLSET(S) float4 pAh##S, pAl##S, pBh0##S, pBl0##S, pBh1##S, pBl1##S

#define LOADREGS(S, k0_) do {                                               \
    int k0v = (k0_);                                                        \
    if (MODE == 0) {                                                        \
        int kk = k0v + ak;                                                  \
        int tap = kk >> 9, ii = kk & 511;                                   \
        int ta = tt0 + tap;                                                 \
        pAh##S = pAl##S = make_float4(0.f, 0.f, 0.f, 0.f);                  \
        if ((unsigned)ta < 2048u) {                                         \
            long o = ((long)bq * 2048 + ta) * 512 + ii;                     \
            pAh##S = *(const float4*)(Ah + o);                              \
            pAl##S = *(const float4*)(Al + o);                              \
        }                                                                   \
    } else {                                                                \
        pAh##S = *(const float4*)(Ah + aoff + k0v);                         \
        pAl##S = *(const float4*)(Al + aoff + k0v);                         \
    }                                                                       \
    pBh0##S = *(const float4*)(Bh + boff0 + k0v);                           \
    pBl0##S = *(const float4*)(Bl + boff0 + k0v);                           \
    pBh1##S = *(const float4*)(Bh + boff1 + k0v);                           \
    pBl1##S = *(const float4*)(Bl + boff1 + k0v);                           \
} while (0)

#define STOREBUF(S, buf) do {                                               \
    *(float4*)&smem[(buf) * 2048 + aw] = pAh##S;                            \
    *(float4*)&smem[4096 + (buf) * 2048 + aw] = pAl##S;                     \
    int b_ = 8192 + (buf) * 4096 + aw;                                      \
    *(float4*)&smem[b_] = pBh0##S;                                          \
    *(float4*)&smem[b_ + 2048] = pBh1##S;                                   \
    *(float4*)&smem[b_ + 8192] = pBl0##S;                                   \
    *(float4*)&smem[b_ + 8192 + 2048] = pBl1##S;                            \
} while (0)

// ---------------------------------------------------------------------------
// MFMA fp16x3 GEMM, BM=64 x BN=128 (MODE 0 / encoder im2row only).
// EXACT round-3 structure -- proven 178 us / zero conflicts / no spill.
// ---------------------------------------------------------------------------
template <int MODE, int NN>
__global__ __launch_bounds__(256, 3) void k_mgemm64(
    const half_t* __restrict__ Ah, const half_t* __restrict__ Al,
    const half_t* __restrict__ Bh, const half_t* __restrict__ Bl,
    const float* __restrict__ bias, const float* __restrict__ res,
    float* __restrict__ Cf, half_t* __restrict__ Ch, half_t* __restrict__ Cl,
    int N, int K) {
    __shared__ __align__(16) half_t smem[24576];
    const int tid = threadIdx.x;
    const int lane = tid & 63, wid = tid >> 6;
    const int wn = wid << 5;
    const int quad = lane >> 4, l16 = lane & 15;

    constexpr int NWG = 256 * NN;
    constexpr int CHUNK = NWG / 8;
    const int lin = blockIdx.x;
    const int tile = (lin & 7) * CHUNK + (lin >> 3);
    const int m0 = (tile / NN) << 6;
    const int n0 = (tile % NN) << 7;

    const int ar = tid >> 2;
    const int ak = (tid & 3) << 3;

    long aoff = 0;
    int tt0 = 0, bq = 0;
    if (MODE == 0) {
        bq = m0 >> 11;
        tt0 = (m0 & 2047) + ar - 3;
    } else {
        aoff = (long)(m0 + ar) * K + ak;
    }
    const long boff0 = (long)(n0 + ar) * K + ak;
    const long boff1 = boff0 + (long)64 * K;

    const int aw = ar * 32 + ((((tid & 3) ^ (ar >> 1)) & 3) << 3);

    DECLSET(0);
    DECLSET(1);

    f32x4 acc1[4][2] = {};
    f32x4 acc2[4][2] = {};
    const int sw = ((quad ^ (l16 >> 1)) & 3) << 3;

    auto compute = [&](int buf) {
        const int ab = buf * 2048 + l16 * 32 + sw;
        const int bb = 8192 + buf * 4096 + (wn + l16) * 32 + sw;
        f16x8 fah[4], fal[4], fgh[2], fgl[2];
#pragma unroll
        for (int f = 0; f < 4; ++f) {
            fah[f] = *(const f16x8*)&smem[ab + f * 512];
            fal[f] = *(const f16x8*)&smem[ab + 4096 + f * 512];
        }
#pragma unroll
        for (int g = 0; g < 2; ++g) {
            fgh[g] = *(const f16x8*)&smem[bb + g * 512];
            fgl[g] = *(const f16x8*)&smem[bb + 8192 + g * 512];
        }
#pragma unroll
        for (int f = 0; f < 4; ++f)
#pragma unroll
            for (int g = 0; g < 2; ++g)
                acc2[f][g] = __builtin_amdgcn_mfma_f32_16x16x32_f16(fah[f], fgl[g], acc2[f][g], 0, 0, 0);
#pragma unroll
        for (int f = 0; f < 4; ++f)
#pragma unroll
            for (int g = 0; g < 2; ++g)
                acc2[f][g] = __builtin_amdgcn_mfma_f32_16x16x32_f16(fal[f], fgh[g], acc2[f][g], 0, 0, 0);
#pragma unroll
        for (int f = 0; f < 4; ++f)
#pragma unroll
            for (int g = 0; g < 2; ++g)
                acc1[f][g] = __builtin_amdgcn_mfma_f32_16x16x32_f16(fah[f], fgh[g], acc1[f][g], 0, 0, 0);
    };

    const int nIter = K >> 5;
    LOADREGS(0, 0);
    LOADREGS(1, 32);
    STOREBUF(0, 0);
    if (nIter > 2) LOADREGS(0, 64);
    for (int it = 0; it < nIter; it += 2) {
        lds_barrier();
        compute(0);
        STOREBUF(1, 1);
        if (it + 3 < nIter) LOADREGS(1, (it + 3) << 5);
        lds_barrier();
        compute(1);
        if (it + 2 < nIter) {
            STOREBUF(0, 0);
            if (it + 4 < nIter) LOADREGS(0, (it + 4) << 5);
        }
    }

    float bv[2];
    bv[0] = bias[n0 + wn + l16];
    bv[1] = bias[n0 + wn + 16 + l16];

#pragma unroll
    for (int f = 0; f < 4; ++f)
#pragma unroll
        for (int g = 0; g < 2; ++g)
#pragma unroll
            for (int r = 0; r < 4; ++r) {
                long row = m0 + f * 16 + quad * 4 + r;
                int col = n0 + wn + g * 16 + l16;
                float v = acc1[f][g][r] + acc2[f][g][r] * LO_INV + bv[g];
                long o = row * N + col;
                if (MODE == 2) v += res[o];
                Cf[o] = v;
            }
}

// ---------------------------------------------------------------------------
// MFMA fp16x3 GEMM "128": BM=128 x BN=128, BK=32, 256 threads = 4 waves
// (2m x 2n), wave tile 64x64 (4x4 frags) -> 48 MFMA/wave/K-step, LDS-read
// bytes per MFMA 341 B (vs 512 mgemm64 / 398 mgemm96). The GEMM family is
// LDS-BANDWIDTH-bound (r5 analysis: per-SIMD MFMA busy ~9%, LDS traffic
// 144-216 KB/CU-K-step ~= the wall time) -- so cut LDS bytes/FLOP and kill
// the ds_write side entirely via global_load_lds DMA staging:
//   - no staging VGPRs, no ds_write issue slots
//   - swizzle preserved by pre-swizzled per-lane SOURCE address (m173):
//     lane l, DMA instr i loads granule g=(l&3)^((l>>3)&3) of row i*16+(l>>2),
//     landing linearly => read-side XOR ((quad^(l16>>1))&3) unchanged.
// Schedule (T3 minimum, race-free): STAGE(next); compute(cur);
// vmcnt(0)+lgkmcnt(0)+barrier. One barrier per K-step; the barrier both
// publishes the next buffer and proves all waves finished reading cur
// before its next overwrite. 64 KB LDS -> 2 blocks/CU. Regs ~212 < 256.
// MODE 1: +bias, exact GELU, fp16 hi/lo out (2-pass smem round-trip)
// MODE 2: +bias, +res, fp32 out
// LDS halves per buf (16384): Ahi@0 Alo@4096 Bhi@8192 Blo@12288.
// ---------------------------------------------------------------------------
template <int MODE, int NT>
__global__ __launch_bounds__(256, 2) void k_mgemm128(
    const half_t* __restrict__ Ah, const half_t* __restrict__ Al,
    const half_t* __restrict__ Bh, const half_t* __restrict__ Bl,
    const float* __restrict__ bias, const float* __restrict__ res,
    float* __restrict__ Cf, half_t* __restrict__ Ch, half_t* __restrict__ Cl,
    int N, int K) {
    __shared__ __align__(16) half_t smem[32768];
    const int tid = threadIdx.x;
    const int lane = tid & 63, wid = tid >> 6;
    const int wm = (wid >> 1) << 6;       // 0 or 64
    const int wn = (wid & 1) << 6;        // 0 or 64
    const int quad = lane >> 4, l16 = lane & 15;

    // XCD-chunked bijective tile mapping (grid % 8 == 0 for all uses)
    constexpr int NWG = 128 * NT;
    constexpr int CHUNK = NWG / 8;
    const int lin = blockIdx.x;
    const int tile = (lin & 7) * CHUNK + (lin >> 3);
    const int m0 = (tile / NT) << 7;
    const int n0 = (tile % NT) << 7;

    // DMA staging: wave role -> plane {Ahi, Alo, Bhi, Blo}; 8 instrs x 1 KB
    // each (16 rows x 32 halves). Per-lane source: row lr=lane>>2 within the
    // 16-row segment, granule lg=(lane&3)^((lane>>3)&3) (the swizzle, since
    // (row>>1)&3 == (lane>>3)&3 for 16-row-aligned segments).
    const int role = wid;
    const half_t* srcp = (role == 0) ? Ah : (role == 1) ? Al
                        : (role == 2) ? Bh : Bl;
    const int row0g = (role < 2) ? m0 : n0;
    const int lr = lane >> 2;
    const int lg = (lane & 3) ^ ((lane >> 3) & 3);
    const half_t* gbase = srcp + (long)(row0g + lr) * K + lg * 8;
    const long kstride = (long)16 * K;   // rows-per-instr advance

#define STAGEDMA(buf, k0_) do {                                             \
    int k0v = (k0_);                                                        \
    _Pragma("unroll")                                                       \
    for (int i_ = 0; i_ < 8; ++i_)                                          \
        gload_lds(gbase + i_ * kstride + k0v,                               \
                  &smem[(buf) * 16384 + role * 4096 + i_ * 512]);           \
} while (0)

    f32x4 acc1[4][4] = {};
    f32x4 acc2[4][4] = {};
    const int sw = ((quad ^ (l16 >> 1)) & 3) << 3;

    auto compute = [&](int buf) {
        const int ab = buf * 16384 + (wm + l16) * 32 + sw;
        const int bb = buf * 16384 + 8192 + (wn + l16) * 32 + sw;
        f16x8 fah[4], fal[4], fgh[4], fgl[4];
#pragma unroll
        for (int f = 0; f < 4; ++f) {
            fah[f] = *(const f16x8*)&smem[ab + f * 512];
            fal[f] = *(const f16x8*)&smem[ab + 4096 + f * 512];
        }
#pragma unroll
        for (int g = 0; g < 4; ++g) {
            fgh[g] = *(const f16x8*)&smem[bb + g * 512];
            fgl[g] = *(const f16x8*)&smem[bb + 4096 + g * 512];
        }
#pragma unroll
        for (int f = 0; f < 4; ++f)
#pragma unroll
            for (int g = 0; g < 4; ++g)
                acc2[f][g] = __builtin_amdgcn_mfma_f32_16x16x32_f16(fah[f], fgl[g], acc2[f][g], 0, 0, 0);
#pragma unroll
        for (int f = 0; f < 4; ++f)
#pragma unroll
            for (int g = 0; g < 4; ++g)
                acc2[f][g] = __builtin_amdgcn_mfma_f32_16x16x32_f16(fal[f], fgh[g], acc2[f][g], 0, 0, 0);
#pragma unroll
        for (int f = 0; f < 4; ++f)
#pragma unroll
            for (int g = 0; g < 4; ++g)
                acc1[f][g] = __builtin_amdgcn_mfma_f32_16x16x32_f16(fah[f], fgh[g], acc1[f][g], 0, 0, 0);
    };

    const int nIter = K >> 5;
    STAGEDMA(0, 0);
    vm_barrier();
    int cur = 0;
    for (int it = 0; it < nIter; ++it) {
        if (it + 1 < nIter) STAGEDMA(cur ^ 1, (it + 1) << 5);
        compute(cur);
        vm_barrier();     // next buf ready + everyone done reading cur
        cur ^= 1;
    }
#undef STAGEDMA

    float bv[4];
#pragma unroll
    for (int g = 0; g < 4; ++g) bv[g] = bias[n0 + wn + g * 16 + l16];

    if (MODE == 1) {
        // GELU + fp16 hi/lo split; 2 row-half passes through smem for
        // coalesced stores. Plane stride 136 halves; hi @0, lo @8704.
#pragma unroll
        for (int p = 0; p < 2; ++p) {
            if ((wid >> 1) == p) {
#pragma unroll
                for (int f = 0; f < 4; ++f)
#pragma unroll
                    for (int g = 0; g < 4; ++g)
#pragma unroll
                        for (int r = 0; r < 4; ++r) {
                            int rm = f * 16 + quad * 4 + r;   // 0..63
                            int cn = wn + g * 16 + l16;
                            float v = acc1[f][g][r] + acc2[f][g][r] * LO_INV + bv[g];
                            v = 0.5f * v * (1.0f + erff(v * 0.70710678118654752f));
                            half_t hh = (half_t)v;
                            smem[rm * 136 + cn] = hh;
                            smem[8704 + rm * 136 + cn] = (half_t)((v - (float)hh) * LO_SCALE);
                        }
            }
            __syncthreads();
            int rrow = tid >> 2, c0 = (tid & 3) << 5;
            long go = (long)(m0 + p * 64 + rrow) * N + n0 + c0;
            int so = rrow * 136 + c0;
#pragma unroll
            for (int u = 0; u < 4; ++u) {
                *(float4*)(Ch + go + u * 8) = *(const float4*)&smem[so + u * 8];
                *(float4*)(Cl + go + u * 8) = *(const float4*)&smem[8704 + so + u * 8];
            }
            __syncthreads();
        }
    } else {
#pragma unroll
        for (int f = 0; f < 4; ++f)
#pragma unroll
            for (int g = 0; g < 4; ++g)
#pragma unroll
                for (int r = 0; r < 4; ++r) {
                    long row = m0 + wm + f * 16 + quad * 4 + r;
                    int col = n0 + wn + g * 16 + l16;
                    float v = acc1[f][g][r] + acc2[f][g][r] * LO_INV + bv[g];
                    long o = row * N + col;
                    v += res[o];
                    Cf[o] = v;
                }
    }
}

// ---------------------------------------------------------------------------
// Fused out-conv (pointwise, C=8) + nearest-embedding argmin over K=8192
// ---------------------------------------------------------------------------
__global__ __launch_bounds__(256) void k_outconv_argmin(
    const float* __restrict__ h, const float* __restrict__ ow,
    const float* __restrict__ ob, const float* __restrict__ emb,
    int* __restrict__ outIdx) {
    __shared__ float hs[16][H_ + 1];
    __shared__ float zs[16][8];
    __shared__ float es[16 * 516];
    __shared__ float rb[16][16];
    __shared__ int ri[16][16];
    const int tid = threadIdx.x;
    const int row0 = blockIdx.x << 4;

    for (int i = tid; i < 16 * (H_ / 4); i += 256) {
        int r = i / 96;
        int c4 = (i % 96) << 2;
        float4 v = *(const float4*)&h[((long)(row0 + r)) * H_ + c4];
        hs[r][c4] = v.x; hs[r][c4 + 1] = v.y; hs[r][c4 + 2] = v.z; hs[r][c4 + 3] = v.w;
    }
    __syncthreads();

    if (tid < 128) {
        int r = tid & 15, c = tid >> 4;
        float acc = ob[c];
        const float* wc = ow + c * H_;
        for (int j = 0; j < H_; ++j) acc = fmaf(hs[r][j], wc[j], acc);
        zs[r][c] = acc;
    }
    __syncthreads();

    const int r = tid & 15;
    const int sl = tid >> 4;
    float z0 = zs[r][0], z1 = zs[r][1], z2 = zs[r][2], z3 = zs[r][3];
    float z4 = zs[r][4], z5 = zs[r][5], z6 = zs[r][6], z7 = zs[r][7];
    float best = 3.4e38f;
    int bi = 0;

    for (int ch = 0; ch < 8; ++ch) {
        __syncthreads();
        for (int i = tid; i < 2048; i += 256) {
            int e = i >> 1;
            int half = (i & 1) << 2;
            float4 src = *(const float4*)&emb[(((long)(ch << 10)) + e) * 8 + half];
            *(float4*)&es[(e >> 6) * 516 + ((e & 63) << 3) + half] = src;
        }
        __syncthreads();
        const float* ep = es + sl * 516;
        int gbase = (ch << 10) + (sl << 6);
#pragma unroll 4
        for (int j = 0; j < 64; ++j) {
            float4 e0 = *(const float4*)(ep + (j << 3));
            float4 e1 = *(const float4*)(ep + (j << 3) + 4);
            float t, d;
            t = e0.x - z0; d = t * t;
            t = e0.y - z1; d = fmaf(t, t, d);
            t = e0.z - z2; d = fmaf(t, t, d);
            t = e0.w - z3; d = fmaf(t, t, d);
            t = e1.x - z4; d = fmaf(t, t, d);
            t = e1.y - z5; d = fmaf(t, t, d);
            t = e1.z - z6; d = fmaf(t, t, d);
            t = e1.w - z7; d = fmaf(t, t, d);
            if (d < best) { best = d; bi = gbase + j; }
        }
    }
    rb[r][sl] = best;
    ri[r][sl] = bi;
    __syncthreads();
    if (sl == 0) {
        float bb = rb[r][0];
        int bbi = ri[r][0];
#pragma unroll
        for (int s2 = 1; s2 < 16; ++s2) {
            float v = rb[r][s2];
            int i2 = ri[r][s2];
            if (v < bb || (v == bb && i2 < bbi)) { bb = v; bbi = i2; }
        }
        outIdx[row0 + r] = bbi;
    }
}

// ---------------------------------------------------------------------------
// host launcher
// ---------------------------------------------------------------------------
extern "C" void kernel_launch(void* const* d_in, const int* in_sizes, int n_in,
                              void* d_out, int out_size, void* d_ws, size_t ws_size,
                              hipStream_t stream) {
    const float* x        = (const float*)d_in[0];
    const float* enc_w    = (const float*)d_in[1];
    const float* enc_b    = (const float*)d_in[2];
    const float* enc_ln_g = (const float*)d_in[3];
    const float* enc_ln_b = (const float*)d_in[4];
    const float* blk_dw_w = (const float*)d_in[5];
    const float* blk_dw_b = (const float*)d_in[6];
    const float* blk_ln_g = (const float*)d_in[7];
    const float* blk_ln_b = (const float*)d_in[8];
    const float* blk_w1   = (const float*)d_in[9];
    const float* blk_b1   = (const float*)d_in[10];
    const float* blk_w2   = (const float*)d_in[11];
    const float* blk_b2   = (const float*)d_in[12];
    const float* out_w    = (const float*)d_in[13];
    const float* out_b    = (const float*)d_in[14];
    const float* emb      = (const float*)d_in[15];
    int* out = (int*)d_out;

    char* base = (char*)d_ws;
    float*  h    = (float*)base;                       // 25165824 B
    half_t* tmph = (half_t*)(base + 25165824);         // 12582912 B
    half_t* tmpl = (half_t*)(base + 37748736);         // 12582912 B
    half_t* ht4h = (half_t*)(base + 50331648);         // 50331648 B
    half_t* ht4l = (half_t*)(base + 100663296);        // 50331648 B
    half_t* ench = (half_t*)(base + 150994944);        // 2752512 B
    half_t* encl = (half_t*)(base + 153747456);        // 2752512 B
    half_t* w1h  = (half_t*)(base + 156499968);        // 7077888 B
    half_t* w1l  = (half_t*)(base + 163577856);        // 7077888 B
    half_t* w2h  = (half_t*)(base + 170655744);        // 7077888 B
    half_t* w2l  = (half_t*)(base + 177733632);        // 7077888 B
    // x hi/lo alias the ht4 region (dead until first GEMM1)
    half_t* xh = ht4h;                                  // 16777216 B
    half_t* xl = (half_t*)(base + 50331648 + 16777216); // 16777216 B

    k_split<<<(8388608 + 255) / 256, 256, 0, stream>>>(x, xh, xl, 8388608L);
    k_split<<<(3538944 + 255) / 256, 256, 0, stream>>>(blk_w1, w1h, w1l, 3538944L);
    k_split<<<(3538944 + 255) / 256, 256, 0, stream>>>(blk_w2, w2h, w2l, 3538944L);
    k_split_encw<<<(H_ * 3584 + 255) / 256, 256, 0, stream>>>(enc_w, ench, encl);

    // encoder conv (im2row MFMA GEMM) -> h, then in-place LN
    k_mgemm64<0, 3><<<768, 256, 0, stream>>>(xh, xl, ench, encl, enc_b,
                                             nullptr, h, nullptr, nullptr,
                                             H_, 3584);
    k_ln<<<BT_, 64, 0, stream>>>(h, h, enc_ln_g, enc_ln_b);

    for (int i = 0; i < 6; ++i) {
        k_dwconv_ln<<<BT_ / 4, 256, 0, stream>>>(h, tmph, tmpl, blk_dw_w + i * H_ * 7,
                                                 blk_dw_b + i * H_, blk_ln_g + i * H_,
                                                 blk_ln_b + i * H_);
        // GEMM1: 128x128 DMA-staged tiles, grid 128m x 12n = 1536 blocks
        k_mgemm128<1, 12><<<1536, 256, 0, stream>>>(
            tmph, tmpl, w1h + (long)i * 589824, w1l + (long)i * 589824,
            blk_b1 + i * H4_, nullptr, nullptr, ht4h, ht4l, H4_, H_);
        // GEMM2: 128x128 DMA-staged tiles, grid 128m x 3n = 384 blocks
        k_mgemm128<2, 3><<<384, 256, 0, stream>>>(
            ht4h, ht4l, w2h + (long)i * 589824, w2l + (long)i * 589824,
            blk_b2 + i * H_, h, h, nullptr, nullptr, H_, H4_);
    }

    k_outconv_argmin<<<BT_ / 16, 256, 0, stream>>>(h, out_w, out_b, emb, out);
}

// Round 7
// 1732.663 us; speedup vs baseline: 1.0114x; 1.0114x over previous
//
#include <hip/hip_runtime.h>
#include <math.h>

#define T_   2048
#define DIN  512
#define H_   384
#define H4_  1536
#define BT_  16384

typedef _Float16 half_t;
typedef _Float16 f16x8 __attribute__((ext_vector_type(8)));
typedef float f32x4 __attribute__((ext_vector_type(4)));

#define LO_SCALE 2048.0f
#define LO_INV   4.8828125e-4f

// lgkm-only barrier: prefetched global->VGPR loads stay in flight across it.
__device__ __forceinline__ void lds_barrier() {
    asm volatile("s_waitcnt lgkmcnt(0)\n\ts_barrier" ::: "memory");
}

// async global->LDS DMA, 16 B per lane (1 KB per wave-instruction).
// LDS dest is wave-uniform base + lane*16 (linear); global src is per-lane.
__device__ __forceinline__ void gload_lds(const half_t* g, half_t* l) {
    __builtin_amdgcn_global_load_lds(
        (const __attribute__((address_space(1))) unsigned int*)(const void*)g,
        (__attribute__((address_space(3))) unsigned int*)(void*)l, 16, 0, 0);
}

__device__ __forceinline__ void split2(float v, half_t* hi, half_t* lo) {
    half_t h = (half_t)v;
    *hi = h;
    *lo = (half_t)((v - (float)h) * LO_SCALE);
}

// ---------------------------------------------------------------------------
// fp32 -> (hi, lo*2048) fp16 element-wise split
// ---------------------------------------------------------------------------
__global__ void k_split(const float* __restrict__ in, half_t* __restrict__ hi,
                        half_t* __restrict__ lo, long n) {
    long i = (long)blockIdx.x * 256 + threadIdx.x;
    if (i >= n) return;
    split2(in[i], hi + i, lo + i);
}

// enc_w [H][DIN][7] -> [H][tap*512+i] hi/lo
__global__ void k_split_encw(const float* __restrict__ in, half_t* __restrict__ hi,
                             half_t* __restrict__ lo) {
    int idx = blockIdx.x * 256 + threadIdx.x;
    if (idx >= H_ * 3584) return;
    int n = idx / 3584;
    int r = idx % 3584;
    int tap = r >> 9, i = r & 511;
    split2(in[n * 3584 + i * 7 + tap], hi + idx, lo + idx);
}

// ---------------------------------------------------------------------------
// Row-wise LayerNorm over H=384 (fp32 in/out, in-place safe), one wave per row
// ---------------------------------------------------------------------------
__global__ void k_ln(const float* __restrict__ in, float* __restrict__ out,
                     const float* __restrict__ g, const float* __restrict__ b) {
    int row = blockIdx.x;
    int lane = threadIdx.x;
    const float* ir = in + (long)row * H_;
    float v[6];
    float s = 0.f;
#pragma unroll
    for (int j = 0; j < 6; ++j) { v[j] = ir[lane + (j << 6)]; s += v[j]; }
#pragma unroll
    for (int o = 32; o > 0; o >>= 1) s += __shfl_down(s, o, 64);
    s = __shfl(s, 0, 64);
    float mean = s * (1.f / 384.f);
    float q = 0.f;
#pragma unroll
    for (int j = 0; j < 6; ++j) { float d = v[j] - mean; q += d * d; }
#pragma unroll
    for (int o = 32; o > 0; o >>= 1) q += __shfl_down(q, o, 64);
    q = __shfl(q, 0, 64);
    float rstd = rsqrtf(q * (1.f / 384.f) + 1e-5f);
    float* orow = out + (long)row * H_;
#pragma unroll
    for (int j = 0; j < 6; ++j) {
        int c = lane + (j << 6);
        orow[c] = (v[j] - mean) * rstd * g[c] + b[c];
    }
}

// ---------------------------------------------------------------------------
// Fused depthwise conv (k=7, pad=3) + LayerNorm; emits fp16 hi/lo for GEMM1.
// float2-vectorized h loads (G13).
// ---------------------------------------------------------------------------
__global__ __launch_bounds__(256) void k_dwconv_ln(
    const float* __restrict__ h, half_t* __restrict__ oh,
    half_t* __restrict__ ol,
    const float* __restrict__ w, const float* __restrict__ wb,
    const float* __restrict__ g, const float* __restrict__ gb) {
    int row = (blockIdx.x << 2) + (threadIdx.x >> 6);
    int b = row >> 11;
    int t = row & 2047;
    int lane = threadIdx.x & 63;
    const float* hb = h + ((long)b * T_) * H_;
    float vx[3], vy[3];
    float s = 0.f;
#pragma unroll
    for (int j = 0; j < 3; ++j) {
        int c = (lane << 1) + (j << 7);
        float ax = wb[c], ay = wb[c + 1];
        const float* wcx = w + c * 7;
        const float* wcy = wcx + 7;
#pragma unroll
        for (int k = 0; k < 7; ++k) {
            int tt = t + k - 3;
            if ((unsigned)tt < (unsigned)T_) {
                float2 hv = *(const float2*)&hb[(long)tt * H_ + c];
                ax = fmaf(hv.x, wcx[k], ax);
                ay = fmaf(hv.y, wcy[k], ay);
            }
        }
        vx[j] = ax; vy[j] = ay;
        s += ax + ay;
    }
#pragma unroll
    for (int o = 32; o > 0; o >>= 1) s += __shfl_down(s, o, 64);
    s = __shfl(s, 0, 64);
    float mean = s * (1.f / 384.f);
    float q = 0.f;
#pragma unroll
    for (int j = 0; j < 3; ++j) {
        float dx = vx[j] - mean, dy = vy[j] - mean;
        q += dx * dx + dy * dy;
    }
#pragma unroll
    for (int o = 32; o > 0; o >>= 1) q += __shfl_down(q, o, 64);
    q = __shfl(q, 0, 64);
    float rstd = rsqrtf(q * (1.f / 384.f) + 1e-5f);
    long ro = (long)row * H_;
#pragma unroll
    for (int j = 0; j < 3; ++j) {
        int c = (lane << 1) + (j << 7);
        float valx = (vx[j] - mean) * rstd * g[c] + gb[c];
        float valy = (vy[j] - mean) * rstd * g[c + 1] + gb[c + 1];
        split2(valx, oh + ro + c, ol + ro + c);
        split2(valy, oh + ro + c + 1, ol + ro + c + 1);
    }
}

// ---------------------------------------------------------------------------
// Prefetch register sets as NAMED float4s via macros (never struct/reference —
// round-1: address-taken sets scratch-spill; rule #20).
// ---------------------------------------------------------------------------
#define DECLSET(S) float4 pAh##S, pAl##S, pBh0##S, pBl0##S, pBh1##S, pBl1##S

#define LOADREGS(S, k0_) do {                                               \
    int k0v = (k0_);                                                        \
    if (MODE == 0) {                                                        \
        int kk = k0v + ak;                                                  \
        int tap = kk >> 9, ii = kk & 511;                                   \
        int ta = tt0 + tap;                                                 \
        pAh##S = pAl##S = make_float4(0.f, 0.f, 0.f, 0.f);                  \
        if ((unsigned)ta < 2048u) {                                         \
            long o = ((long)bq * 2048 + ta) * 512 + ii;                     \
            pAh##S = *(const float4*)(Ah + o);                              \
            pAl##S = *(const float4*)(Al + o);                              \
        }                                                                   \
    } else {                                                                \
        pAh##S = *(const float4*)(Ah + aoff + k0v);                         \
        pAl##S = *(const float4*)(Al + aoff + k0v);                         \
    }                                                                       \
    pBh0##S = *(const float4*)(Bh + boff0 + k0v);                           \
    pBl0##S = *(const float4*)(Bl + boff0 + k0v);                           \
    pBh1##S = *(const float4*)(Bh + boff1 + k0v);                           \
    pBl1##S = *(const float4*)(Bl + boff1 + k0v);                           \
} while (0)

#define STOREBUF(S, buf) do {                                               \
    *(float4*)&smem[(buf) * 2048 + aw] = pAh##S;                            \
    *(float4*)&smem[4096 + (buf) * 2048 + aw] = pAl##S;                     \
    int b_ = 8192 + (buf) * 4096 + aw;                                      \
    *(float4*)&smem[b_] = pBh0##S;                                          \
    *(float4*)&smem[b_ + 2048] = pBh1##S;                                   \
    *(float4*)&smem[b_ + 8192] = pBl0##S;                                   \
    *(float4*)&smem[b_ + 8192 + 2048] = pBl1##S;                            \
} while (0)

// ---------------------------------------------------------------------------
// MFMA fp16x3 GEMM, BM=64 x BN=128 (MODE 0 / encoder im2row only).
// EXACT round-3 structure -- proven 178 us / zero conflicts / no spill.
// ---------------------------------------------------------------------------
template <int MODE, int NN>
__global__ __launch_bounds__(256, 3) void k_mgemm64(
    const half_t* __restrict__ Ah, const half_t* __restrict__ Al,
    const half_t* __restrict__ Bh, const half_t* __restrict__ Bl,
    const float* __restrict__ bias, const float* __restrict__ res,
    float* __restrict__ Cf, half_t* __restrict__ Ch, half_t* __restrict__ Cl,
    int N, int K) {
    __shared__ __align__(16) half_t smem[24576];
    const int tid = threadIdx.x;
    const int lane = tid & 63, wid = tid >> 6;
    const int wn = wid << 5;
    const int quad = lane >> 4, l16 = lane & 15;

    constexpr int NWG = 256 * NN;
    constexpr int CHUNK = NWG / 8;
    const int lin = blockIdx.x;
    const int tile = (lin & 7) * CHUNK + (lin >> 3);
    const int m0 = (tile / NN) << 6;
    const int n0 = (tile % NN) << 7;

    const int ar = tid >> 2;
    const int ak = (tid & 3) << 3;

    long aoff = 0;
    int tt0 = 0, bq = 0;
    if (MODE == 0) {
        bq = m0 >> 11;
        tt0 = (m0 & 2047) + ar - 3;
    } else {
        aoff = (long)(m0 + ar) * K + ak;
    }
    const long boff0 = (long)(n0 + ar) * K + ak;
    const long boff1 = boff0 + (long)64 * K;

    const int aw = ar * 32 + ((((tid & 3) ^ (ar >> 1)) & 3) << 3);

    DECLSET(0);
    DECLSET(1);

    f32x4 acc1[4][2] = {};
    f32x4 acc2[4][2] = {};
    const int sw = ((quad ^ (l16 >> 1)) & 3) << 3;

    auto compute = [&](int buf) {
        const int ab = buf * 2048 + l16 * 32 + sw;
        const int bb = 8192 + buf * 4096 + (wn + l16) * 32 + sw;
        f16x8 fah[4], fal[4], fgh[2], fgl[2];
#pragma unroll
        for (int f = 0; f < 4; ++f) {
            fah[f] = *(const f16x8*)&smem[ab + f * 512];
            fal[f] = *(const f16x8*)&smem[ab + 4096 + f * 512];
        }
#pragma unroll
        for (int g = 0; g < 2; ++g) {
            fgh[g] = *(const f16x8*)&smem[bb + g * 512];
            fgl[g] = *(const f16x8*)&smem[bb + 8192 + g * 512];
        }
#pragma unroll
        for (int f = 0; f < 4; ++f)
#pragma unroll
            for (int g = 0; g < 2; ++g)
                acc2[f][g] = __builtin_amdgcn_mfma_f32_16x16x32_f16(fah[f], fgl[g], acc2[f][g], 0, 0, 0);
#pragma unroll
        for (int f = 0; f < 4; ++f)
#pragma unroll
            for (int g = 0; g < 2; ++g)
                acc2[f][g] = __builtin_amdgcn_mfma_f32_16x16x32_f16(fal[f], fgh[g], acc2[f][g], 0, 0, 0);
#pragma unroll
        for (int f = 0; f < 4; ++f)
#pragma unroll
            for (int g = 0; g < 2; ++g)
                acc1[f][g] = __builtin_amdgcn_mfma_f32_16x16x32_f16(fah[f], fgh[g], acc1[f][g], 0, 0, 0);
    };

    const int nIter = K >> 5;
    LOADREGS(0, 0);
    LOADREGS(1, 32);
    STOREBUF(0, 0);
    if (nIter > 2) LOADREGS(0, 64);
    for (int it = 0; it < nIter; it += 2) {
        lds_barrier();
        compute(0);
        STOREBUF(1, 1);
        if (it + 3 < nIter) LOADREGS(1, (it + 3) << 5);
        lds_barrier();
        compute(1);
        if (it + 2 < nIter) {
            STOREBUF(0, 0);
            if (it + 4 < nIter) LOADREGS(0, (it + 4) << 5);
        }
    }

    float bv[2];
    bv[0] = bias[n0 + wn + l16];
    bv[1] = bias[n0 + wn + 16 + l16];

#pragma unroll
    for (int f = 0; f < 4; ++f)
#pragma unroll
        for (int g = 0; g < 2; ++g)
#pragma unroll
            for (int r = 0; r < 4; ++r) {
                long row = m0 + f * 16 + quad * 4 + r;
                int col = n0 + wn + g * 16 + l16;
                float v = acc1[f][g][r] + acc2[f][g][r] * LO_INV + bv[g];
                long o = row * N + col;
                if (MODE == 2) v += res[o];
                Cf[o] = v;
            }
}

// ---------------------------------------------------------------------------
// MFMA fp16x3 GEMM "g192" (T3+T4): BM=128 x BN=192, BK=32, 512 threads =
// 8 waves (2m x 4n), wave tile 64x48 (4x3 frags, 36 MFMA/wave/K-step).
// DMA staging (global_load_lds, pre-swizzled per-lane source -- r6-proven),
// RING-3 LDS (3 x 40 KB = 120 KB, 1 block/CU, 2 waves/SIMD) with COUNTED
// vmcnt: stage tile t+2 while computing tile t; main-loop wait is
// vmcnt(10) (= own 5 DMA/tile x 2 tiles still in flight), never 0 --
// loads span 2 full compute phases (~2800 cyc) vs the r6 drain-0 (~0 cyc).
// This is the catalog's T4 lever (counted-vs-drain0 = +38..73% at m218);
// the whole session's 2-phase variants sat at the documented ~30-36% wall.
// 2 raw barriers/K-step: #1 after vmcnt (publish tile t), #2 after compute
// (all reads of buf t consumed before any wave's next STAGE overwrites it:
// STAGE at iter t+1 targets buf (t+3)%3 == t%3).
// Staging map: 40 segments of 16 rows x 32 halves {Ahi 8, Alo 8, Bhi 12,
// Blo 12}; wave w owns segments 5w..5w+4 (uniform 5 DMA/tile/wave).
// nIter must be >= 3 (G1: 12, G2: 48). Grids exact: G1 128x8=1024 (4
// rounds), G2 128x2=256 (1 round, no tail).
// MODE 1: +bias, exact GELU, fp16 hi/lo out (smem round-trip, stride 200)
// MODE 2: +bias, +res, fp32 out
// Buf layout (halves, stride 20480): Ahi@0 Alo@4096 Bhi@8192 Blo@14336.
// ---------------------------------------------------------------------------
template <int MODE, int NT>
__global__ __launch_bounds__(512, 2) void k_g192(
    const half_t* __restrict__ Ah, const half_t* __restrict__ Al,
    const half_t* __restrict__ Bh, const half_t* __restrict__ Bl,
    const float* __restrict__ bias, const float* __restrict__ res,
    float* __restrict__ Cf, half_t* __restrict__ Ch, half_t* __restrict__ Cl,
    int N, int K) {
    __shared__ __align__(16) half_t smem[61440];
    const int tid = threadIdx.x;
    const int lane = tid & 63, wid = tid >> 6;
    const int wm = (wid & 1) << 6;          // {0, 64}
    const int wn = ((wid >> 1) & 3) * 48;   // {0, 48, 96, 144}
    const int quad = lane >> 4, l16 = lane & 15;

    // XCD-chunked bijective tile mapping (grid % 8 == 0)
    constexpr int NWG = 128 * NT;
    constexpr int CHUNK = NWG / 8;
    const int lin = blockIdx.x;
    const int tile = (lin & 7) * CHUNK + (lin >> 3);
    const int m0 = (tile / NT) << 7;
    const int n0 = (tile % NT) * 192;

    // per-lane DMA source swizzle (m173): lane l loads granule
    // lg=(l&3)^((l>>3)&3) of row lr=l>>2 of its 16-row segment; lands
    // linearly so slot s of row r holds granule s^((r>>1)&3) -- matches the
    // read-side XOR below (verified r6, absmax 0).
    const int lr = lane >> 2;
    const int lg = (lane & 3) ^ ((lane >> 3) & 3);
    const half_t* gsrc[5];
    int ldo[5];
#pragma unroll
    for (int j = 0; j < 5; ++j) {
        int q = wid * 5 + j;
        const half_t* sp;
        long r0;
        int lo_;
        if (q < 8)       { sp = Ah; r0 = m0 + q * 16;        lo_ = q * 512; }
        else if (q < 16) { sp = Al; r0 = m0 + (q - 8) * 16;  lo_ = 4096 + (q - 8) * 512; }
        else if (q < 28) { sp = Bh; r0 = n0 + (q - 16) * 16; lo_ = 8192 + (q - 16) * 512; }
        else             { sp = Bl; r0 = n0 + (q - 28) * 16; lo_ = 14336 + (q - 28) * 512; }
        gsrc[j] = sp + (r0 + lr) * (long)K + lg * 8;
        ldo[j] = lo_;
    }

#define STAGE3(bufb, k0_) do {                                              \
    int k0v = (k0_);                                                        \
    _Pragma("unroll")                                                       \
    for (int j = 0; j < 5; ++j)                                             \
        gload_lds(gsrc[j] + k0v, &smem[(bufb) + ldo[j]]);                   \
} while (0)

    f32x4 acc1[4][3] = {};
    f32x4 acc2[4][3] = {};
    const int sw = ((quad ^ (l16 >> 1)) & 3) << 3;

    auto compute = [&](int bufb) {
        const int ab = bufb + (wm + l16) * 32 + sw;
        const int bb = bufb + 8192 + (wn + l16) * 32 + sw;
        f16x8 fah[4], fal[4], fgh[3], fgl[3];
#pragma unroll
        for (int f = 0; f < 4; ++f) {
            fah[f] = *(const f16x8*)&smem[ab + f * 512];
            fal[f] = *(const f16x8*)&smem[ab + 4096 + f * 512];
        }
#pragma unroll
        for (int g = 0; g < 3; ++g) {
            fgh[g] = *(const f16x8*)&smem[bb + g * 512];
            fgl[g] = *(const f16x8*)&smem[bb + 6144 + g * 512];
        }
#pragma unroll
        for (int f = 0; f < 4; ++f)
#pragma unroll
            for (int g = 0; g < 3; ++g)
                acc2[f][g] = __builtin_amdgcn_mfma_f32_16x16x32_f16(fah[f], fgl[g], acc2[f][g], 0, 0, 0);
#pragma unroll
        for (int f = 0; f < 4; ++f)
#pragma unroll
            for (int g = 0; g < 3; ++g)
                acc2[f][g] = __builtin_amdgcn_mfma_f32_16x16x32_f16(fal[f], fgh[g], acc2[f][g], 0, 0, 0);
#pragma unroll
        for (int f = 0; f < 4; ++f)
#pragma unroll
            for (int g = 0; g < 3; ++g)
                acc1[f][g] = __builtin_amdgcn_mfma_f32_16x16x32_f16(fah[f], fgh[g], acc1[f][g], 0, 0, 0);
    };

    const int nIter = K >> 5;   // 12 (G1) / 48 (G2); must be >= 3
    STAGE3(0, 0);
    STAGE3(20480, 32);
    int b0 = 0, b1 = 20480, b2 = 40960;
    for (int it = 0; it + 2 < nIter; ++it) {
        STAGE3(b2, (it + 2) << 5);
        asm volatile("s_waitcnt vmcnt(10)" ::: "memory");   // tile it landed
        __builtin_amdgcn_s_barrier();                       // all waves' too
        compute(b0);
        __builtin_amdgcn_s_barrier();                       // reads consumed
        int t_ = b0; b0 = b1; b1 = b2; b2 = t_;
    }
    // tail: tiles nIter-2, nIter-1 (no staging, counted then full drain)
    asm volatile("s_waitcnt vmcnt(5)" ::: "memory");
    __builtin_amdgcn_s_barrier();
    compute(b0);
    asm volatile("s_waitcnt vmcnt(0)" ::: "memory");
    __builtin_amdgcn_s_barrier();
    compute(b1);
#undef STAGE3

    float bv[3];
#pragma unroll
    for (int g = 0; g < 3; ++g) bv[g] = bias[n0 + wn + g * 16 + l16];

    if (MODE == 1) {
        // GELU + fp16 hi/lo split; smem round-trip (reuses ring buffers --
        // sync first). Row stride 200 halves (400 B, 16B-aligned);
        // hi @0, lo @25600. Max use 51191 < 61440.
        __syncthreads();
#pragma unroll
        for (int f = 0; f < 4; ++f)
#pragma unroll
            for (int g = 0; g < 3; ++g)
#pragma unroll
                for (int r = 0; r < 4; ++r) {
                    int rm = wm + f * 16 + quad * 4 + r;
                    int cn = wn + g * 16 + l16;
                    float v = acc1[f][g][r] + acc2[f][g][r] * LO_INV + bv[g];
                    v = 0.5f * v * (1.0f + erff(v * 0.70710678118654752f));
                    half_t hh = (half_t)v;
                    smem[rm * 200 + cn] = hh;
                    smem[25600 + rm * 200 + cn] = (half_t)((v - (float)hh) * LO_SCALE);
                }
        __syncthreads();
        int row = tid >> 2, c0 = (tid & 3) * 48;
        long go = (long)(m0 + row) * N + n0 + c0;
        int so = row * 200 + c0;
#pragma unroll
        for (int u = 0; u < 6; ++u) {
            *(float4*)(Ch + go + u * 8) = *(const float4*)&smem[so + u * 8];
            *(float4*)(Cl + go + u * 8) = *(const float4*)&smem[25600 + so + u * 8];
        }
    } else {
#pragma unroll
        for (int f = 0; f < 4; ++f)
#pragma unroll
            for (int g = 0; g < 3; ++g)
#pragma unroll
                for (int r = 0; r < 4; ++r) {
                    long row = m0 + wm + f * 16 + quad * 4 + r;
                    int col = n0 + wn + g * 16 + l16;
                    float v = acc1[f][g][r] + acc2[f][g][r] * LO_INV + bv[g];
                    long o = row * N + col;
                    v += res[o];
                    Cf[o] = v;
                }
    }
}

// ---------------------------------------------------------------------------
// Fused out-conv (pointwise, C=8) + nearest-embedding argmin over K=8192
// ---------------------------------------------------------------------------
__global__ __launch_bounds__(256) void k_outconv_argmin(
    const float* __restrict__ h, const float* __restrict__ ow,
    const float* __restrict__ ob, const float* __restrict__ emb,
    int* __restrict__ outIdx) {
    __shared__ float hs[16][H_ + 1];
    __shared__ float zs[16][8];
    __shared__ float es[16 * 516];
    __shared__ float rb[16][16];
    __shared__ int ri[16][16];
    const int tid = threadIdx.x;
    const int row0 = blockIdx.x << 4;

    for (int i = tid; i < 16 * (H_ / 4); i += 256) {
        int r = i / 96;
        int c4 = (i % 96) << 2;
        float4 v = *(const float4*)&h[((long)(row0 + r)) * H_ + c4];
        hs[r][c4] = v.x; hs[r][c4 + 1] = v.y; hs[r][c4 + 2] = v.z; hs[r][c4 + 3] = v.w;
    }
    __syncthreads();

    if (tid < 128) {
        int r = tid & 15, c = tid >> 4;
        float acc = ob[c];
        const float* wc = ow + c * H_;
        for (int j = 0; j < H_; ++j) acc = fmaf(hs[r][j], wc[j], acc);
        zs[r][c] = acc;
    }
    __syncthreads();

    const int r = tid & 15;
    const int sl = tid >> 4;
    float z0 = zs[r][0], z1 = zs[r][1], z2 = zs[r][2], z3 = zs[r][3];
    float z4 = zs[r][4], z5 = zs[r][5], z6 = zs[r][6], z7 = zs[r][7];
    float best = 3.4e38f;
    int bi = 0;

    for (int ch = 0; ch < 8; ++ch) {
        __syncthreads();
        for (int i = tid; i < 2048; i += 256) {
            int e = i >> 1;
            int half = (i & 1) << 2;
            float4 src = *(const float4*)&emb[(((long)(ch << 10)) + e) * 8 + half];
            *(float4*)&es[(e >> 6) * 516 + ((e & 63) << 3) + half] = src;
        }
        __syncthreads();
        const float* ep = es + sl * 516;
        int gbase = (ch << 10) + (sl << 6);
#pragma unroll 4
        for (int j = 0; j < 64; ++j) {
            float4 e0 = *(const float4*)(ep + (j << 3));
            float4 e1 = *(const float4*)(ep + (j << 3) + 4);
            float t, d;
            t = e0.x - z0; d = t * t;
            t = e0.y - z1; d = fmaf(t, t, d);
            t = e0.z - z2; d = fmaf(t, t, d);
            t = e0.w - z3; d = fmaf(t, t, d);
            t = e1.x - z4; d = fmaf(t, t, d);
            t = e1.y - z5; d = fmaf(t, t, d);
            t = e1.z - z6; d = fmaf(t, t, d);
            t = e1.w - z7; d = fmaf(t, t, d);
            if (d < best) { best = d; bi = gbase + j; }
        }
    }
    rb[r][sl] = best;
    ri[r][sl] = bi;
    __syncthreads();
    if (sl == 0) {
        float bb = rb[r][0];
        int bbi = ri[r][0];
#pragma unroll
        for (int s2 = 1; s2 < 16; ++s2) {
            float v = rb[r][s2];
            int i2 = ri[r][s2];
            if (v < bb || (v == bb && i2 < bbi)) { bb = v; bbi = i2; }
        }
        outIdx[row0 + r] = bbi;
    }
}

// ---------------------------------------------------------------------------
// host launcher
// ---------------------------------------------------------------------------
extern "C" void kernel_launch(void* const* d_in, const int* in_sizes, int n_in,
                              void* d_out, int out_size, void* d_ws, size_t ws_size,
                              hipStream_t stream) {
    const float* x        = (const float*)d_in[0];
    const float* enc_w    = (const float*)d_in[1];
    const float* enc_b    = (const float*)d_in[2];
    const float* enc_ln_g = (const float*)d_in[3];
    const float* enc_ln_b = (const float*)d_in[4];
    const float* blk_dw_w = (const float*)d_in[5];
    const float* blk_dw_b = (const float*)d_in[6];
    const float* blk_ln_g = (const float*)d_in[7];
    const float* blk_ln_b = (const float*)d_in[8];
    const float* blk_w1   = (const float*)d_in[9];
    const float* blk_b1   = (const float*)d_in[10];
    const float* blk_w2   = (const float*)d_in[11];
    const float* blk_b2   = (const float*)d_in[12];
    const float* out_w    = (const float*)d_in[13];
    const float* out_b    = (const float*)d_in[14];
    const float* emb      = (const float*)d_in[15];
    int* out = (int*)d_out;

    char* base = (char*)d_ws;
    float*  h    = (float*)base;                       // 25165824 B
    half_t* tmph = (half_t*)(base + 25165824);         // 12582912 B
    half_t* tmpl = (half_t*)(base + 37748736);         // 12582912 B
    half_t* ht4h = (half_t*)(base + 50331648);         // 50331648 B
    half_t* ht4l = (half_t*)(base + 100663296);        // 50331648 B
    half_t* ench = (half_t*)(base + 150994944);        // 2752512 B
    half_t* encl = (half_t*)(base + 153747456);        // 2752512 B
    half_t* w1h  = (half_t*)(base + 156499968);        // 7077888 B
    half_t* w1l  = (half_t*)(base + 163577856);        // 7077888 B
    half_t* w2h  = (half_t*)(base + 170655744);        // 7077888 B
    half_t* w2l  = (half_t*)(base + 177733632);        // 7077888 B
    // x hi/lo alias the ht4 region (dead until first GEMM1)
    half_t* xh = ht4h;                                  // 16777216 B
    half_t* xl = (half_t*)(base + 50331648 + 16777216); // 16777216 B

    k_split<<<(8388608 + 255) / 256, 256, 0, stream>>>(x, xh, xl, 8388608L);
    k_split<<<(3538944 + 255) / 256, 256, 0, stream>>>(blk_w1, w1h, w1l, 3538944L);
    k_split<<<(3538944 + 255) / 256, 256, 0, stream>>>(blk_w2, w2h, w2l, 3538944L);
    k_split_encw<<<(H_ * 3584 + 255) / 256, 256, 0, stream>>>(enc_w, ench, encl);

    // encoder conv (im2row MFMA GEMM) -> h, then in-place LN
    k_mgemm64<0, 3><<<768, 256, 0, stream>>>(xh, xl, ench, encl, enc_b,
                                             nullptr, h, nullptr, nullptr,
                                             H_, 3584);
    k_ln<<<BT_, 64, 0, stream>>>(h, h, enc_ln_g, enc_ln_b);

    for (int i = 0; i < 6; ++i) {
        k_dwconv_ln<<<BT_ / 4, 256, 0, stream>>>(h, tmph, tmpl, blk_dw_w + i * H_ * 7,
                                                 blk_dw_b + i * H_, blk_ln_g + i * H_,
                                                 blk_ln_b + i * H_);
        // GEMM1: 128x192 ring-3 counted-vmcnt tiles; 128m x 8n = 1024 blocks
        k_g192<1, 8><<<1024, 512, 0, stream>>>(
            tmph, tmpl, w1h + (long)i * 589824, w1l + (long)i * 589824,
            blk_b1 + i * H4_, nullptr, nullptr, ht4h, ht4l, H4_, H_);
        // GEMM2: 128x192 tiles; 128m x 2n = 256 blocks = 1 exact round
        k_g192<2, 2><<<256, 512, 0, stream>>>(
            ht4h, ht4l, w2h + (long)i * 589824, w2l + (long)i * 589824,
            blk_b2 + i * H_, h, h, nullptr, nullptr, H_, H4_);
    }

    k_outconv_argmin<<<BT_ / 16, 256, 0, stream>>>(h, out_w, out_b, emb, out);
}

// Round 8
// 1642.406 us; speedup vs baseline: 1.0670x; 1.0550x over previous
//
#include <hip/hip_runtime.h>
#include <math.h>

#define T_   2048
#define DIN  512
#define H_   384
#define H4_  1536
#define BT_  16384

typedef _Float16 half_t;
typedef _Float16 f16x8 __attribute__((ext_vector_type(8)));
typedef _Float16 f16x4 __attribute__((ext_vector_type(4)));
typedef float f32x4 __attribute__((ext_vector_type(4)));

#define LO_SCALE 2048.0f
#define LO_INV   4.8828125e-4f

// lgkm-only barrier: prefetched global->VGPR loads stay in flight across it.
__device__ __forceinline__ void lds_barrier() {
    asm volatile("s_waitcnt lgkmcnt(0)\n\ts_barrier" ::: "memory");
}

// async global->LDS DMA, 16 B per lane (1 KB per wave-instruction).
__device__ __forceinline__ void gload_lds(const half_t* g, half_t* l) {
    __builtin_amdgcn_global_load_lds(
        (const __attribute__((address_space(1))) unsigned int*)(const void*)g,
        (__attribute__((address_space(3))) unsigned int*)(void*)l, 16, 0, 0);
}

__device__ __forceinline__ void split2(float v, half_t* hi, half_t* lo) {
    half_t h = (half_t)v;
    *hi = h;
    *lo = (half_t)((v - (float)h) * LO_SCALE);
}

// ---------------------------------------------------------------------------
// fp32 -> (hi, lo*2048) fp16 split, 4 elems/thread (G13 vectorized)
// ---------------------------------------------------------------------------
__global__ void k_split4(const float* __restrict__ in, half_t* __restrict__ hi,
                         half_t* __restrict__ lo, long n4) {
    long i = (long)blockIdx.x * 256 + threadIdx.x;
    if (i >= n4) return;
    float4 v = ((const float4*)in)[i];
    f16x4 vh, vl;
    float a[4] = {v.x, v.y, v.z, v.w};
#pragma unroll
    for (int j = 0; j < 4; ++j) {
        half_t h = (half_t)a[j];
        vh[j] = h;
        vl[j] = (half_t)((a[j] - (float)h) * LO_SCALE);
    }
    ((f16x4*)hi)[i] = vh;
    ((f16x4*)lo)[i] = vl;
}

// enc_w [H][DIN][7] -> [H][tap*512+i] hi/lo
__global__ void k_split_encw(const float* __restrict__ in, half_t* __restrict__ hi,
                             half_t* __restrict__ lo) {
    int idx = blockIdx.x * 256 + threadIdx.x;
    if (idx >= H_ * 3584) return;
    int n = idx / 3584;
    int r = idx % 3584;
    int tap = r >> 9, i = r & 511;
    split2(in[n * 3584 + i * 7 + tap], hi + idx, lo + idx);
}

// ---------------------------------------------------------------------------
// Row-wise LayerNorm over H=384 (fp32 in/out, in-place safe), one wave per row
// ---------------------------------------------------------------------------
__global__ void k_ln(const float* __restrict__ in, float* __restrict__ out,
                     const float* __restrict__ g, const float* __restrict__ b) {
    int row = blockIdx.x;
    int lane = threadIdx.x;
    const float* ir = in + (long)row * H_;
    float v[6];
    float s = 0.f;
#pragma unroll
    for (int j = 0; j < 6; ++j) { v[j] = ir[lane + (j << 6)]; s += v[j]; }
#pragma unroll
    for (int o = 32; o > 0; o >>= 1) s += __shfl_down(s, o, 64);
    s = __shfl(s, 0, 64);
    float mean = s * (1.f / 384.f);
    float q = 0.f;
#pragma unroll
    for (int j = 0; j < 6; ++j) { float d = v[j] - mean; q += d * d; }
#pragma unroll
    for (int o = 32; o > 0; o >>= 1) q += __shfl_down(q, o, 64);
    q = __shfl(q, 0, 64);
    float rstd = rsqrtf(q * (1.f / 384.f) + 1e-5f);
    float* orow = out + (long)row * H_;
#pragma unroll
    for (int j = 0; j < 6; ++j) {
        int c = lane + (j << 6);
        orow[c] = (v[j] - mean) * rstd * g[c] + b[c];
    }
}

// ---------------------------------------------------------------------------
// Fused depthwise conv (k=7, pad=3) + LayerNorm; emits fp16 hi/lo for GEMM1.
// float2-vectorized h loads (G13).
// ---------------------------------------------------------------------------
__global__ __launch_bounds__(256) void k_dwconv_ln(
    const float* __restrict__ h, half_t* __restrict__ oh,
    half_t* __restrict__ ol,
    const float* __restrict__ w, const float* __restrict__ wb,
    const float* __restrict__ g, const float* __restrict__ gb) {
    int row = (blockIdx.x << 2) + (threadIdx.x >> 6);
    int b = row >> 11;
    int t = row & 2047;
    int lane = threadIdx.x & 63;
    const float* hb = h + ((long)b * T_) * H_;
    float vx[3], vy[3];
    float s = 0.f;
#pragma unroll
    for (int j = 0; j < 3; ++j) {
        int c = (lane << 1) + (j << 7);
        float ax = wb[c], ay = wb[c + 1];
        const float* wcx = w + c * 7;
        const float* wcy = wcx + 7;
#pragma unroll
        for (int k = 0; k < 7; ++k) {
            int tt = t + k - 3;
            if ((unsigned)tt < (unsigned)T_) {
                float2 hv = *(const float2*)&hb[(long)tt * H_ + c];
                ax = fmaf(hv.x, wcx[k], ax);
                ay = fmaf(hv.y, wcy[k], ay);
            }
        }
        vx[j] = ax; vy[j] = ay;
        s += ax + ay;
    }
#pragma unroll
    for (int o = 32; o > 0; o >>= 1) s += __shfl_down(s, o, 64);
    s = __shfl(s, 0, 64);
    float mean = s * (1.f / 384.f);
    float q = 0.f;
#pragma unroll
    for (int j = 0; j < 3; ++j) {
        float dx = vx[j] - mean, dy = vy[j] - mean;
        q += dx * dx + dy * dy;
    }
#pragma unroll
    for (int o = 32; o > 0; o >>= 1) q += __shfl_down(q, o, 64);
    q = __shfl(q, 0, 64);
    float rstd = rsqrtf(q * (1.f / 384.f) + 1e-5f);
    long ro = (long)row * H_;
#pragma unroll
    for (int j = 0; j < 3; ++j) {
        int c = (lane << 1) + (j << 7);
        float valx = (vx[j] - mean) * rstd * g[c] + gb[c];
        float valy = (vy[j] - mean) * rstd * g[c + 1] + gb[c + 1];
        split2(valx, oh + ro + c, ol + ro + c);
        split2(valy, oh + ro + c + 1, ol + ro + c + 1);
    }
}

// ---------------------------------------------------------------------------
// Prefetch register sets as NAMED float4s via macros (rule #20).
// ---------------------------------------------------------------------------
#define DECLSET(S) float4 pAh##S, pAl##S, pBh0##S, pBl0##S, pBh1##S, pBl1##S

#define LOADREGS(S, k0_) do {                                               \
    int k0v = (k0_);                                                        \
    if (MODE == 0) {                                                        \
        int kk = k0v + ak;                                                  \
        int tap = kk >> 9, ii = kk & 511;                                   \
        int ta = tt0 + tap;                                                 \
        pAh##S = pAl##S = make_float4(0.f, 0.f, 0.f, 0.f);                  \
        if ((unsigned)ta < 2048u) {                                         \
            long o = ((long)bq * 2048 + ta) * 512 + ii;                     \
            pAh##S = *(const float4*)(Ah + o);                              \
            pAl##S = *(const float4*)(Al + o);                              \
        }                                                                   \
    } else {                                                                \
        pAh##S = *(const float4*)(Ah + aoff + k0v);                         \
        pAl##S = *(const float4*)(Al + aoff + k0v);                         \
    }                                                                       \
    pBh0##S = *(const float4*)(Bh + boff0 + k0v);                           \
    pBl0##S = *(const float4*)(Bl + boff0 + k0v);                           \
    pBh1##S = *(const float4*)(Bh + boff1 + k0v);                           \
    pBl1##S = *(const float4*)(Bl + boff1 + k0v);                           \
} while (0)

#define STOREBUF(S, buf) do {                                               \
    *(float4*)&smem[(buf) * 2048 + aw] = pAh##S;                            \
    *(float4*)&smem[4096 + (buf) * 2048 + aw] = pAl##S;                     \
    int b_ = 8192 + (buf) * 4096 + aw;                                      \
    *(float4*)&smem[b_] = pBh0##S;                                          \
    *(float4*)&smem[b_ + 2048] = pBh1##S;                                   \
    *(float4*)&smem[b_ + 8192] = pBl0##S;                                   \
    *(float4*)&smem[b_ + 8192 + 2048] = pBl1##S;                            \
} while (0)

// ---------------------------------------------------------------------------
// MFMA fp16x3 GEMM, BM=64 x BN=128 (MODE 0 / encoder im2row only).
// EXACT round-3 structure -- proven 178 us / zero conflicts / no spill.
// ---------------------------------------------------------------------------
template <int MODE, int NN>
__global__ __launch_bounds__(256, 3) void k_mgemm64(
    const half_t* __restrict__ Ah, const half_t* __restrict__ Al,
    const half_t* __restrict__ Bh, const half_t* __restrict__ Bl,
    const float* __restrict__ bias, const float* __restrict__ res,
    float* __restrict__ Cf, half_t* __restrict__ Ch, half_t* __restrict__ Cl,
    int N, int K) {
    __shared__ __align__(16) half_t smem[24576];
    const int tid = threadIdx.x;
    const int lane = tid & 63, wid = tid >> 6;
    const int wn = wid << 5;
    const int quad = lane >> 4, l16 = lane & 15;

    constexpr int NWG = 256 * NN;
    constexpr int CHUNK = NWG / 8;
    const int lin = blockIdx.x;
    const int tile = (lin & 7) * CHUNK + (lin >> 3);
    const int m0 = (tile / NN) << 6;
    const int n0 = (tile % NN) << 7;

    const int ar = tid >> 2;
    const int ak = (tid & 3) << 3;

    long aoff = 0;
    int tt0 = 0, bq = 0;
    if (MODE == 0) {
        bq = m0 >> 11;
        tt0 = (m0 & 2047) + ar - 3;
    } else {
        aoff = (long)(m0 + ar) * K + ak;
    }
    const long boff0 = (long)(n0 + ar) * K + ak;
    const long boff1 = boff0 + (long)64 * K;

    const int aw = ar * 32 + ((((tid & 3) ^ (ar >> 1)) & 3) << 3);

    DECLSET(0);
    DECLSET(1);

    f32x4 acc1[4][2] = {};
    f32x4 acc2[4][2] = {};
    const int sw = ((quad ^ (l16 >> 1)) & 3) << 3;

    auto compute = [&](int buf) {
        const int ab = buf * 2048 + l16 * 32 + sw;
        const int bb = 8192 + buf * 4096 + (wn + l16) * 32 + sw;
        f16x8 fah[4], fal[4], fgh[2], fgl[2];
#pragma unroll
        for (int f = 0; f < 4; ++f) {
            fah[f] = *(const f16x8*)&smem[ab + f * 512];
            fal[f] = *(const f16x8*)&smem[ab + 4096 + f * 512];
        }
#pragma unroll
        for (int g = 0; g < 2; ++g) {
            fgh[g] = *(const f16x8*)&smem[bb + g * 512];
            fgl[g] = *(const f16x8*)&smem[bb + 8192 + g * 512];
        }
#pragma unroll
        for (int f = 0; f < 4; ++f)
#pragma unroll
            for (int g = 0; g < 2; ++g)
                acc2[f][g] = __builtin_amdgcn_mfma_f32_16x16x32_f16(fah[f], fgl[g], acc2[f][g], 0, 0, 0);
#pragma unroll
        for (int f = 0; f < 4; ++f)
#pragma unroll
            for (int g = 0; g < 2; ++g)
                acc2[f][g] = __builtin_amdgcn_mfma_f32_16x16x32_f16(fal[f], fgh[g], acc2[f][g], 0, 0, 0);
#pragma unroll
        for (int f = 0; f < 4; ++f)
#pragma unroll
            for (int g = 0; g < 2; ++g)
                acc1[f][g] = __builtin_amdgcn_mfma_f32_16x16x32_f16(fah[f], fgh[g], acc1[f][g], 0, 0, 0);
    };

    const int nIter = K >> 5;
    LOADREGS(0, 0);
    LOADREGS(1, 32);
    STOREBUF(0, 0);
    if (nIter > 2) LOADREGS(0, 64);
    for (int it = 0; it < nIter; it += 2) {
        lds_barrier();
        compute(0);
        STOREBUF(1, 1);
        if (it + 3 < nIter) LOADREGS(1, (it + 3) << 5);
        lds_barrier();
        compute(1);
        if (it + 2 < nIter) {
            STOREBUF(0, 0);
            if (it + 4 < nIter) LOADREGS(0, (it + 4) << 5);
        }
    }

    float bv[2];
    bv[0] = bias[n0 + wn + l16];
    bv[1] = bias[n0 + wn + 16 + l16];

#pragma unroll
    for (int f = 0; f < 4; ++f)
#pragma unroll
        for (int g = 0; g < 2; ++g)
#pragma unroll
            for (int r = 0; r < 4; ++r) {
                long row = m0 + f * 16 + quad * 4 + r;
                int col = n0 + wn + g * 16 + l16;
                float v = acc1[f][g][r] + acc2[f][g][r] * LO_INV + bv[g];
                long o = row * N + col;
                if (MODE == 2) v += res[o];
                Cf[o] = v;
            }
}

// ---------------------------------------------------------------------------
// MFMA fp16x3 GEMM "g192p" -- r7's g192 skeleton + the FINE per-phase
// interleave (the missing T3 ingredient; m196: counted-vmcnt with coarse
// phases is null, the per-phase {reads ∥ stage -> barrier -> MFMA cluster}
// is the lever). 3 phases per K-step from the fp16x3 algebra:
//   P1: ds_read Ah(4)+Bl(3), stage 2/5 DMA(t+2) -> bar -> 12 MFMA (Ah*Bl)
//   P2: ds_read Al(4)+Bh(3), stage 3/5 DMA      -> bar -> 12 MFMA (Al*Bh)
//   P3: (frags live)                                   -> 12 MFMA (Ah*Bh)
// vmcnt(5) + barrier at iter start (counted: tile t+1's 5 DMAs stay in
// flight; drain-0 only at the last iter). setprio around each cluster (T5
// pays only on phase-split schedules, m218b). sched_barrier(0) at phase
// boundaries stops hipcc re-flattening the reads (rule #18 analog).
// Ring-3 safety unchanged from r7 (verified absmax 0): a wave's reads of a
// buffer retire before its iter-start barrier; the overwrite issues after.
// Geometry/staging map/swizzle/epilogues identical to r7.
// ---------------------------------------------------------------------------
template <int MODE, int NT>
__global__ __launch_bounds__(512, 2) void k_g192p(
    const half_t* __restrict__ Ah, const half_t* __restrict__ Al,
    const half_t* __restrict__ Bh, const half_t* __restrict__ Bl,
    const float* __restrict__ bias, const float* __restrict__ res,
    float* __restrict__ Cf, half_t* __restrict__ Ch, half_t* __restrict__ Cl,
    int N, int K) {
    __shared__ __align__(16) half_t smem[61440];
    const int tid = threadIdx.x;
    const int lane = tid & 63, wid = tid >> 6;
    const int wm = (wid & 1) << 6;          // {0, 64}
    const int wn = ((wid >> 1) & 3) * 48;   // {0, 48, 96, 144}
    const int quad = lane >> 4, l16 = lane & 15;

    constexpr int NWG = 128 * NT;
    constexpr int CHUNK = NWG / 8;
    const int lin = blockIdx.x;
    const int tile = (lin & 7) * CHUNK + (lin >> 3);
    const int m0 = (tile / NT) << 7;
    const int n0 = (tile % NT) * 192;

    // per-lane DMA source swizzle (m173, r6/r7-verified)
    const int lr = lane >> 2;
    const int lg = (lane & 3) ^ ((lane >> 3) & 3);
    const half_t* gsrc[5];
    int ldo[5];
#pragma unroll
    for (int j = 0; j < 5; ++j) {
        int q = wid * 5 + j;
        const half_t* sp;
        long r0;
        int lo_;
        if (q < 8)       { sp = Ah; r0 = m0 + q * 16;        lo_ = q * 512; }
        else if (q < 16) { sp = Al; r0 = m0 + (q - 8) * 16;  lo_ = 4096 + (q - 8) * 512; }
        else if (q < 28) { sp = Bh; r0 = n0 + (q - 16) * 16; lo_ = 8192 + (q - 16) * 512; }
        else             { sp = Bl; r0 = n0 + (q - 28) * 16; lo_ = 14336 + (q - 28) * 512; }
        gsrc[j] = sp + (r0 + lr) * (long)K + lg * 8;
        ldo[j] = lo_;
    }

#define STAGE3(bufb, k0_) do {                                              \
    int k0v = (k0_);                                                        \
    _Pragma("unroll")                                                       \
    for (int j = 0; j < 5; ++j)                                             \
        gload_lds(gsrc[j] + k0v, &smem[(bufb) + ldo[j]]);                   \
} while (0)

    f32x4 acc1[4][3] = {};
    f32x4 acc2[4][3] = {};
    const int sw = ((quad ^ (l16 >> 1)) & 3) << 3;

    const int nIter = K >> 5;   // 12 (G1) / 48 (G2); must be >= 3
    STAGE3(0, 0);
    STAGE3(20480, 32);
    int b0 = 0, b1 = 20480, b2 = 40960;
    for (int it = 0; it < nIter; ++it) {
        // tile `it` landed: outstanding = tile it+1's 5 (counted, never 0
        // except final iter)
        if (it + 1 < nIter)
            asm volatile("s_waitcnt vmcnt(5)" ::: "memory");
        else
            asm volatile("s_waitcnt vmcnt(0)" ::: "memory");
        __builtin_amdgcn_s_barrier();
        __builtin_amdgcn_sched_barrier(0);

        const int ab = b0 + (wm + l16) * 32 + sw;
        const int bb = b0 + 8192 + (wn + l16) * 32 + sw;
        const int k2 = (it + 2) << 5;
        const bool st = (it + 2 < nIter);
        f16x8 fah[4], fal[4], fgh[3], fgl[3];

        // ---- P1: Ah + Bl reads, 2/5 staging, 12 MFMA (Ah*Bl)
#pragma unroll
        for (int f = 0; f < 4; ++f)
            fah[f] = *(const f16x8*)&smem[ab + f * 512];
#pragma unroll
        for (int g = 0; g < 3; ++g)
            fgl[g] = *(const f16x8*)&smem[bb + 6144 + g * 512];
        if (st) {
            gload_lds(gsrc[0] + k2, &smem[b2 + ldo[0]]);
            gload_lds(gsrc[1] + k2, &smem[b2 + ldo[1]]);
        }
        __builtin_amdgcn_s_barrier();
        __builtin_amdgcn_sched_barrier(0);
        __builtin_amdgcn_s_setprio(1);
#pragma unroll
        for (int f = 0; f < 4; ++f)
#pragma unroll
            for (int g = 0; g < 3; ++g)
                acc2[f][g] = __builtin_amdgcn_mfma_f32_16x16x32_f16(fah[f], fgl[g], acc2[f][g], 0, 0, 0);
        __builtin_amdgcn_s_setprio(0);
        __builtin_amdgcn_sched_barrier(0);
        __builtin_amdgcn_s_barrier();

        // ---- P2: Al + Bh reads, 3/5 staging, 12 MFMA (Al*Bh)
#pragma unroll
        for (int f = 0; f < 4; ++f)
            fal[f] = *(const f16x8*)&smem[ab + 4096 + f * 512];
#pragma unroll
        for (int g = 0; g < 3; ++g)
            fgh[g] = *(const f16x8*)&smem[bb + g * 512];
        if (st) {
            gload_lds(gsrc[2] + k2, &smem[b2 + ldo[2]]);
            gload_lds(gsrc[3] + k2, &smem[b2 + ldo[3]]);
            gload_lds(gsrc[4] + k2, &smem[b2 + ldo[4]]);
        }
        __builtin_amdgcn_s_barrier();
        __builtin_amdgcn_sched_barrier(0);
        __builtin_amdgcn_s_setprio(1);
#pragma unroll
        for (int f = 0; f < 4; ++f)
#pragma unroll
            for (int g = 0; g < 3; ++g)
                acc2[f][g] = __builtin_amdgcn_mfma_f32_16x16x32_f16(fal[f], fgh[g], acc2[f][g], 0, 0, 0);
        __builtin_amdgcn_s_setprio(0);
        __builtin_amdgcn_sched_barrier(0);
        __builtin_amdgcn_s_barrier();

        // ---- P3: 12 MFMA (Ah*Bh), no reads
        __builtin_amdgcn_s_setprio(1);
#pragma unroll
        for (int f = 0; f < 4; ++f)
#pragma unroll
            for (int g = 0; g < 3; ++g)
                acc1[f][g] = __builtin_amdgcn_mfma_f32_16x16x32_f16(fah[f], fgh[g], acc1[f][g], 0, 0, 0);
        __builtin_amdgcn_s_setprio(0);
        __builtin_amdgcn_sched_barrier(0);

        int t_ = b0; b0 = b1; b1 = b2; b2 = t_;
    }
#undef STAGE3

    float bv[3];
#pragma unroll
    for (int g = 0; g < 3; ++g) bv[g] = bias[n0 + wn + g * 16 + l16];

    if (MODE == 1) {
        // GELU + fp16 hi/lo split; smem round-trip, row stride 200 halves,
        // hi @0, lo @25600. (r7-verified epilogue.)
        __syncthreads();
#pragma unroll
        for (int f = 0; f < 4; ++f)
#pragma unroll
            for (int g = 0; g < 3; ++g)
#pragma unroll
                for (int r = 0; r < 4; ++r) {
                    int rm = wm + f * 16 + quad * 4 + r;
                    int cn = wn + g * 16 + l16;
                    float v = acc1[f][g][r] + acc2[f][g][r] * LO_INV + bv[g];
                    v = 0.5f * v * (1.0f + erff(v * 0.70710678118654752f));
                    half_t hh = (half_t)v;
                    smem[rm * 200 + cn] = hh;
                    smem[25600 + rm * 200 + cn] = (half_t)((v - (float)hh) * LO_SCALE);
                }
        __syncthreads();
        int row = tid >> 2, c0 = (tid & 3) * 48;
        long go = (long)(m0 + row) * N + n0 + c0;
        int so = row * 200 + c0;
#pragma unroll
        for (int u = 0; u < 6; ++u) {
            *(float4*)(Ch + go + u * 8) = *(const float4*)&smem[so + u * 8];
            *(float4*)(Cl + go + u * 8) = *(const float4*)&smem[25600 + so + u * 8];
        }
    } else {
#pragma unroll
        for (int f = 0; f < 4; ++f)
#pragma unroll
            for (int g = 0; g < 3; ++g)
#pragma unroll
                for (int r = 0; r < 4; ++r) {
                    long row = m0 + wm + f * 16 + quad * 4 + r;
                    int col = n0 + wn + g * 16 + l16;
                    float v = acc1[f][g][r] + acc2[f][g][r] * LO_INV + bv[g];
                    long o = row * N + col;
                    v += res[o];
                    Cf[o] = v;
                }
    }
}

// ---------------------------------------------------------------------------
// Fused out-conv (pointwise, C=8) + nearest-embedding argmin over K=8192
// ---------------------------------------------------------------------------
__global__ __launch_bounds__(256) void k_outconv_argmin(
    const float* __restrict__ h, const float* __restrict__ ow,
    const float* __restrict__ ob, const float* __restrict__ emb,
    int* __restrict__ outIdx) {
    __shared__ float hs[16][H_ + 1];
    __shared__ float zs[16][8];
    __shared__ float es[16 * 516];
    __shared__ float rb[16][16];
    __shared__ int ri[16][16];
    const int tid = threadIdx.x;
    const int row0 = blockIdx.x << 4;

    for (int i = tid; i < 16 * (H_ / 4); i += 256) {
        int r = i / 96;
        int c4 = (i % 96) << 2;
        float4 v = *(const float4*)&h[((long)(row0 + r)) * H_ + c4];
        hs[r][c4] = v.x; hs[r][c4 + 1] = v.y; hs[r][c4 + 2] = v.z; hs[r][c4 + 3] = v.w;
    }
    __syncthreads();

    if (tid < 128) {
        int r = tid & 15, c = tid >> 4;
        float acc = ob[c];
        const float* wc = ow + c * H_;
        for (int j = 0; j < H_; ++j) acc = fmaf(hs[r][j], wc[j], acc);
        zs[r][c] = acc;
    }
    __syncthreads();

    const int r = tid & 15;
    const int sl = tid >> 4;
    float z0 = zs[r][0], z1 = zs[r][1], z2 = zs[r][2], z3 = zs[r][3];
    float z4 = zs[r][4], z5 = zs[r][5], z6 = zs[r][6], z7 = zs[r][7];
    float best = 3.4e38f;
    int bi = 0;

    for (int ch = 0; ch < 8; ++ch) {
        __syncthreads();
        for (int i = tid; i < 2048; i += 256) {
            int e = i >> 1;
            int half = (i & 1) << 2;
            float4 src = *(const float4*)&emb[(((long)(ch << 10)) + e) * 8 + half];
            *(float4*)&es[(e >> 6) * 516 + ((e & 63) << 3) + half] = src;
        }
        __syncthreads();
        const float* ep = es + sl * 516;
        int gbase = (ch << 10) + (sl << 6);
#pragma unroll 4
        for (int j = 0; j < 64; ++j) {
            float4 e0 = *(const float4*)(ep + (j << 3));
            float4 e1 = *(const float4*)(ep + (j << 3) + 4);
            float t, d;
            t = e0.x - z0; d = t * t;
            t = e0.y - z1; d = fmaf(t, t, d);
            t = e0.z - z2; d = fmaf(t, t, d);
            t = e0.w - z3; d = fmaf(t, t, d);
            t = e1.x - z4; d = fmaf(t, t, d);
            t = e1.y - z5; d = fmaf(t, t, d);
            t = e1.z - z6; d = fmaf(t, t, d);
            t = e1.w - z7; d = fmaf(t, t, d);
            if (d < best) { best = d; bi = gbase + j; }
        }
    }
    rb[r][sl] = best;
    ri[r][sl] = bi;
    __syncthreads();
    if (sl == 0) {
        float bb = rb[r][0];
        int bbi = ri[r][0];
#pragma unroll
        for (int s2 = 1; s2 < 16; ++s2) {
            float v = rb[r][s2];
            int i2 = ri[r][s2];
            if (v < bb || (v == bb && i2 < bbi)) { bb = v; bbi = i2; }
        }
        outIdx[row0 + r] = bbi;
    }
}

// ---------------------------------------------------------------------------
// host launcher
// ---------------------------------------------------------------------------
extern "C" void kernel_launch(void* const* d_in, const int* in_sizes, int n_in,
                              void* d_out, int out_size, void* d_ws, size_t ws_size,
                              hipStream_t stream) {
    const float* x        = (const float*)d_in[0];
    const float* enc_w    = (const float*)d_in[1];
    const float* enc_b    = (const float*)d_in[2];
    const float* enc_ln_g = (const float*)d_in[3];
    const float* enc_ln_b = (const float*)d_in[4];
    const float* blk_dw_w = (const float*)d_in[5];
    const float* blk_dw_b = (const float*)d_in[6];
    const float* blk_ln_g = (const float*)d_in[7];
    const float* blk_ln_b = (const float*)d_in[8];
    const float* blk_w1   = (const float*)d_in[9];
    const float* blk_b1   = (const float*)d_in[10];
    const float* blk_w2   = (const float*)d_in[11];
    const float* blk_b2   = (const float*)d_in[12];
    const float* out_w    = (const float*)d_in[13];
    const float* out_b    = (const float*)d_in[14];
    const float* emb      = (const float*)d_in[15];
    int* out = (int*)d_out;

    char* base = (char*)d_ws;
    float*  h    = (float*)base;                       // 25165824 B
    half_t* tmph = (half_t*)(base + 25165824);         // 12582912 B
    half_t* tmpl = (half_t*)(base + 37748736);         // 12582912 B
    half_t* ht4h = (half_t*)(base + 50331648);         // 50331648 B
    half_t* ht4l = (half_t*)(base + 100663296);        // 50331648 B
    half_t* ench = (half_t*)(base + 150994944);        // 2752512 B
    half_t* encl = (half_t*)(base + 153747456);        // 2752512 B
    half_t* w1h  = (half_t*)(base + 156499968);        // 7077888 B
    half_t* w1l  = (half_t*)(base + 163577856);        // 7077888 B
    half_t* w2h  = (half_t*)(base + 170655744);        // 7077888 B
    half_t* w2l  = (half_t*)(base + 177733632);        // 7077888 B
    // x hi/lo alias the ht4 region (dead until first GEMM1)
    half_t* xh = ht4h;                                  // 16777216 B
    half_t* xl = (half_t*)(base + 50331648 + 16777216); // 16777216 B

    k_split4<<<8192, 256, 0, stream>>>(x, xh, xl, 2097152L);
    k_split4<<<3456, 256, 0, stream>>>(blk_w1, w1h, w1l, 884736L);
    k_split4<<<3456, 256, 0, stream>>>(blk_w2, w2h, w2l, 884736L);
    k_split_encw<<<(H_ * 3584 + 255) / 256, 256, 0, stream>>>(enc_w, ench, encl);

    // encoder conv (im2row MFMA GEMM) -> h, then in-place LN
    k_mgemm64<0, 3><<<768, 256, 0, stream>>>(xh, xl, ench, encl, enc_b,
                                             nullptr, h, nullptr, nullptr,
                                             H_, 3584);
    k_ln<<<BT_, 64, 0, stream>>>(h, h, enc_ln_g, enc_ln_b);

    for (int i = 0; i < 6; ++i) {
        k_dwconv_ln<<<BT_ / 4, 256, 0, stream>>>(h, tmph, tmpl, blk_dw_w + i * H_ * 7,
                                                 blk_dw_b + i * H_, blk_ln_g + i * H_,
                                                 blk_ln_b + i * H_);
        // GEMM1: 128x192 3-phase counted-vmcnt tiles; 128m x 8n = 1024 blocks
        k_g192p<1, 8><<<1024, 512, 0, stream>>>(
            tmph, tmpl, w1h + (long)i * 589824, w1l + (long)i * 589824,
            blk_b1 + i * H4_, nullptr, nullptr, ht4h, ht4l, H4_, H_);
        // GEMM2: 128x192 tiles; 128m x 2n = 256 blocks = 1 exact round
        k_g192p<2, 2><<<256, 512, 0, stream>>>(
            ht4h, ht4l, w2h + (long)i * 589824, w2l + (long)i * 589824,
            blk_b2 + i * H_, h, h, nullptr, nullptr, H_, H4_);
    }

    k_outconv_argmin<<<BT_ / 16, 256, 0, stream>>>(h, out_w, out_b, emb, out);
}